// Round 15
// baseline (125.351 us; speedup 1.0000x reference)
//
#include <hip/hip_runtime.h>
#include <hip/hip_bf16.h>
#include <stdint.h>

#define N_PTS   4096
#define M_CODES 4096
#define ZDIM    1024
// fp8 tiled layout: elem (r,k) at seg(rb)*16384 + kg*128 + r16*8 + ke  (BYTES)
//   rb=r>>4, r16=r&15, kg=k>>3, ke=k&7. Seg = 16 rows x 1024 k = 16 KB.

typedef __attribute__((ext_vector_type(4))) float f32x4;

__device__ __forceinline__ unsigned enc_f32(float f) {
    unsigned u = __float_as_uint(f);
    return (u & 0x80000000u) ? ~u : (u | 0x80000000u);
}
__device__ __forceinline__ float dec_f32(unsigned e) {
    unsigned u = (e & 0x80000000u) ? (e ^ 0x80000000u) : ~u;
    return __uint_as_float(u);
}

// ---------------------------------------------------------------------------
// prep: fp32 -> fp8 e4m3 + tiled layout + fp32 row sum-of-squares
// (R14-proven, unchanged). One block = 16 rows; grid 512.
// ---------------------------------------------------------------------------
#define PREP_PITCH_B 1040   // bytes per LDS row: 1024 + 16 pad
__global__ __launch_bounds__(256) void prep_kernel(
    const float* __restrict__ z, const float* __restrict__ e,
    uint8_t* __restrict__ zb, uint8_t* __restrict__ eb,
    float* __restrict__ zsq, float* __restrict__ esq,
    unsigned* __restrict__ min_enc) {
    __shared__ uint8_t tile[16 * PREP_PITCH_B];   // ~16.6 KB
    __shared__ float redbuf[16 * 4];

    const int t = threadIdx.x;
    const int b = blockIdx.x;
    if (b < 16) min_enc[b * 256 + t] = 0xFFFFFFFFu;

    const bool is_z = b < 256;
    const int rb = b & 255;
    const float* src = (is_z ? z : e) + (size_t)rb * 16 * ZDIM;
    uint8_t* dst = (is_z ? zb : eb) + (size_t)rb * 16384;   // 16 KB seg
    const int w = t >> 6, lane = t & 63;

    #pragma unroll
    for (int it = 0; it < 16; it++) {
        float4 v = reinterpret_cast<const float4*>(src + (size_t)it * ZDIM)[t];
        int pk = 0;
        pk = __builtin_amdgcn_cvt_pk_fp8_f32(v.x, v.y, pk, false);
        pk = __builtin_amdgcn_cvt_pk_fp8_f32(v.z, v.w, pk, true);
        *reinterpret_cast<int*>(&tile[it * PREP_PITCH_B + t * 4]) = pk;
        float s = v.x * v.x + v.y * v.y + v.z * v.z + v.w * v.w;
        #pragma unroll
        for (int off = 1; off < 64; off <<= 1) s += __shfl_xor(s, off, 64);
        if (lane == 0) redbuf[it * 4 + w] = s;
    }
    __syncthreads();

    #pragma unroll
    for (int it2 = 0; it2 < 8; it2++) {
        const int c = it2 * 256 + t;          // 0..2047
        const int kg = c >> 4, r16 = c & 15;
        const unsigned long long val = *reinterpret_cast<const unsigned long long*>(
            &tile[r16 * PREP_PITCH_B + kg * 8]);
        *reinterpret_cast<unsigned long long*>(&dst[(size_t)c * 8]) = val;
    }
    if (t < 16) {
        float sq = redbuf[t * 4] + redbuf[t * 4 + 1] +
                   redbuf[t * 4 + 2] + redbuf[t * 4 + 3];
        const int row = rb * 16 + t;
        if (is_z) zsq[row] = sq; else esq[row] = sq;
    }
}

// ---------------------------------------------------------------------------
// gemm_min (fp8, HIGH-OCCUPANCY): 64x128 tile, grid (32,64) = 2048 blocks.
// R14 null result proved bytes don't bind (fp8 halved all byte terms,
// total unchanged) — the kernel is LATENCY-bound at 4 waves/SIMD. This
// round: smaller tile + __launch_bounds__(256,6) -> 6 blocks/CU = 24
// waves/CU (1.5x). Same proven structure: single-barrier double-buffered
// A-DMA (8 stages of K=128), A via LDS ds_read_b64 (2-way alias = free),
// B direct from global (lane-linear). 4 waves = 2x2 of 32x64, acc[2][4].
// ---------------------------------------------------------------------------
__global__ __launch_bounds__(256, 6) void gemm_min_kernel(
    const uint8_t* __restrict__ zb, const uint8_t* __restrict__ eb,
    const float* __restrict__ zsq, unsigned* __restrict__ min_enc) {
    __shared__ __align__(16) uint8_t As[16384];  // 2 x 8 KB (4 segs x 2 KB)
    __shared__ float zsq_s[64];
    __shared__ float colmin[2][128];

    const int t = threadIdx.x;        // 0..255
    const int bx = blockIdx.x;        // code (col) block, 0..31
    const int by = blockIdx.y;        // point (row) block, 0..63
    const int lane = t & 63;
    const int w = t >> 6;             // 0..3
    const int wm = w >> 1, wn = w & 1;
    const int lrow = lane & 15;
    const int q = lane >> 4;

    if (t < 64) zsq_s[t] = zsq[by * 64 + t];

    f32x4 acc[2][4];
    #pragma unroll
    for (int i = 0; i < 2; i++)
        #pragma unroll
        for (int j = 0; j < 4; j++) acc[i][j] = (f32x4){0.f, 0.f, 0.f, 0.f};

    // A staging: per stage 8 KB = 4 segs x 2 KB run; 2 instrs/thread.
    // instr j: seg = j*2 + (t>>7); inner = (t&127)*16 (wave-uniform base +
    // lane*16 at the LDS dest — DMA constraint satisfied).
    const int seg_half = t >> 7;            // 0..1
    const int inner = (t & 127) * 16;       // byte offset in 2 KB run
    const size_t a_seg0 = (size_t)(by * 4) * 16384;

    // B base: lane byte addr = lane*8 (lane-linear 512 B per fragment read).
    const uint8_t* b_base =
        eb + (size_t)(bx * 8 + wn * 4) * 16384 + lane * 8;

#define DMA_STAGE(st_)                                                        \
    {                                                                         \
        const int buf_ = ((st_) & 1) * 8192;                                  \
        const int koff_ = (st_) * 2048;  /* byte offset within seg */         \
        _Pragma("unroll")                                                     \
        for (int j = 0; j < 2; j++) {                                         \
            const int seg_ = j * 2 + seg_half;                                \
            const uint8_t* ga = zb + a_seg0 +                                 \
                (size_t)seg_ * 16384 + koff_ + inner;                         \
            __builtin_amdgcn_global_load_lds(                                 \
                (const __attribute__((address_space(1))) void*)ga,            \
                (__attribute__((address_space(3))) void*)(As + buf_ +         \
                    seg_ * 2048 + inner), 16, 0, 0);                          \
        }                                                                     \
    }

    DMA_STAGE(0);
    for (int st = 0; st < 8; st++) {
        __syncthreads();                 // drains DMA(st)
        if (st < 7) DMA_STAGE(st + 1);   // overlaps with compute(st)
        const int buf = (st & 1) * 8192;
        const int koff = st * 2048;
        #pragma unroll
        for (int sl = 0; sl < 4; sl++) {   // four K=32 slices
            long a[2], bb[4];
            #pragma unroll
            for (int an = 0; an < 4; an++)
                bb[an] = *(const long*)(b_base + (size_t)an * 16384 +
                                        koff + sl * 512);
            #pragma unroll
            for (int am = 0; am < 2; am++)
                a[am] = *(const long*)(As + buf + (wm * 2 + am) * 2048 +
                                       sl * 512 + lane * 8);
            #pragma unroll
            for (int am = 0; am < 2; am++)
                #pragma unroll
                for (int an = 0; an < 4; an++)
                    acc[am][an] = __builtin_amdgcn_mfma_f32_16x16x32_fp8_fp8(
                        a[am], bb[an], acc[am][an], 0, 0, 0);
        }
    }
#undef DMA_STAGE

    __syncthreads();

    // Epilogue (proven; C/D layout shape-determined): row = q*4+r, col = lrow.
    #pragma unroll
    for (int an = 0; an < 4; an++) {
        float v = 3.4e38f;
        #pragma unroll
        for (int am = 0; am < 2; am++) {
            const int rbase = wm * 32 + am * 16 + q * 4;
            f32x4 c = acc[am][an];
            v = fminf(v, zsq_s[rbase + 0] - 2.f * c[0]);
            v = fminf(v, zsq_s[rbase + 1] - 2.f * c[1]);
            v = fminf(v, zsq_s[rbase + 2] - 2.f * c[2]);
            v = fminf(v, zsq_s[rbase + 3] - 2.f * c[3]);
        }
        v = fminf(v, __shfl_xor(v, 16, 64));
        v = fminf(v, __shfl_xor(v, 32, 64));
        if (q == 0) colmin[wm][wn * 64 + an * 16 + lrow] = v;
    }
    __syncthreads();
    if (t < 128) {
        const float m = fminf(colmin[0][t], colmin[1][t]);
        atomicMin(&min_enc[bx * 128 + t], enc_f32(m));
    }
}

// ---------------------------------------------------------------------------
// finalize: mean_j (dec(min_enc[j]) + esq[j]) -> single fp32 scalar.
// ---------------------------------------------------------------------------
__global__ __launch_bounds__(256) void finalize_kernel(
    const unsigned* __restrict__ min_enc, const float* __restrict__ esq,
    float* __restrict__ out) {
    const int t = threadIdx.x;
    float s = 0.f;
    #pragma unroll
    for (int i = 0; i < M_CODES / 256; i++) {
        const int j = i * 256 + t;
        s += dec_f32(min_enc[j]) + esq[j];
    }
    #pragma unroll
    for (int off = 1; off < 64; off <<= 1) s += __shfl_xor(s, off, 64);
    __shared__ float red[4];
    if ((t & 63) == 0) red[t >> 6] = s;
    __syncthreads();
    if (t == 0) out[0] = (red[0] + red[1] + red[2] + red[3]) * (1.f / M_CODES);
}

extern "C" void kernel_launch(void* const* d_in, const int* in_sizes, int n_in,
                              void* d_out, int out_size, void* d_ws, size_t ws_size,
                              hipStream_t stream) {
    (void)in_sizes; (void)n_in; (void)out_size; (void)ws_size;
    const float* z = (const float*)d_in[0];
    const float* e = (const float*)d_in[1];
    char* ws = (char*)d_ws;
    uint8_t* zb = (uint8_t*)ws;                                          // 4 MB
    uint8_t* eb = (uint8_t*)(ws + ((size_t)4 << 20));                    // 4 MB
    float* zsq = (float*)(ws + ((size_t)8 << 20));                       // 16 KB
    float* esq = (float*)(ws + ((size_t)8 << 20) + 16384);               // 16 KB
    unsigned* min_enc = (unsigned*)(ws + ((size_t)8 << 20) + 32768);     // 16 KB

    prep_kernel<<<dim3(512), dim3(256), 0, stream>>>(
        z, e, zb, eb, zsq, esq, min_enc);
    gemm_min_kernel<<<dim3(32, 64), dim3(256), 0, stream>>>(
        zb, eb, zsq, min_enc);
    finalize_kernel<<<dim3(1), dim3(256), 0, stream>>>(min_enc, esq, (float*)d_out);
}

// Round 16
// 112.743 us; speedup vs baseline: 1.1118x; 1.1118x over previous
//
#include <hip/hip_runtime.h>
#include <hip/hip_bf16.h>
#include <stdint.h>

#define N_PTS   4096
#define M_CODES 4096
#define ZDIM    1024
// fp8 tiled layout: elem (r,k) at seg(rb)*16384 + kg*128 + r16*8 + ke  (BYTES)
//   rb=r>>4, r16=r&15, kg=k>>3, ke=k&7. Chunk (rb,kg) = 16 rows x 8 k = 128 B.
//   Seg = 16 rows x 1024 k x 1 B = 16 KB.

typedef __attribute__((ext_vector_type(4))) float f32x4;

__device__ __forceinline__ unsigned enc_f32(float f) {
    unsigned u = __float_as_uint(f);
    return (u & 0x80000000u) ? ~u : (u | 0x80000000u);
}
__device__ __forceinline__ float dec_f32(unsigned e) {
    unsigned u = (e & 0x80000000u) ? (e ^ 0x80000000u) : ~u;
    return __uint_as_float(u);
}

// ---------------------------------------------------------------------------
// prep: fp32 -> fp8 e4m3 (OCP) + tiled layout + row sum-of-squares (fp32,
// pre-quantization). One block = 16 rows. grid 512 (256 z + 256 e).
// (R14-proven champion, byte-identical.)
// ---------------------------------------------------------------------------
#define PREP_PITCH_B 1040   // bytes per LDS row: 1024 + 16 pad
__global__ __launch_bounds__(256) void prep_kernel(
    const float* __restrict__ z, const float* __restrict__ e,
    uint8_t* __restrict__ zb, uint8_t* __restrict__ eb,
    float* __restrict__ zsq, float* __restrict__ esq,
    unsigned* __restrict__ min_enc) {
    __shared__ uint8_t tile[16 * PREP_PITCH_B];   // ~16.6 KB
    __shared__ float redbuf[16 * 4];

    const int t = threadIdx.x;
    const int b = blockIdx.x;
    if (b < 16) min_enc[b * 256 + t] = 0xFFFFFFFFu;

    const bool is_z = b < 256;
    const int rb = b & 255;
    const float* src = (is_z ? z : e) + (size_t)rb * 16 * ZDIM;
    uint8_t* dst = (is_z ? zb : eb) + (size_t)rb * 16384;   // 16 KB seg
    const int w = t >> 6, lane = t & 63;

    // Phase 1: coalesced loads, fp32 row sums, pack 4 floats -> 1 dword fp8.
    #pragma unroll
    for (int it = 0; it < 16; it++) {
        float4 v = reinterpret_cast<const float4*>(src + (size_t)it * ZDIM)[t];
        int pk = 0;
        pk = __builtin_amdgcn_cvt_pk_fp8_f32(v.x, v.y, pk, false);
        pk = __builtin_amdgcn_cvt_pk_fp8_f32(v.z, v.w, pk, true);
        *reinterpret_cast<int*>(&tile[it * PREP_PITCH_B + t * 4]) = pk;
        float s = v.x * v.x + v.y * v.y + v.z * v.z + v.w * v.w;
        #pragma unroll
        for (int off = 1; off < 64; off <<= 1) s += __shfl_xor(s, off, 64);
        if (lane == 0) redbuf[it * 4 + w] = s;
    }
    __syncthreads();

    // Phase 2: transpose-store to tiled global (chunk c -> dst + c*8, linear).
    #pragma unroll
    for (int it2 = 0; it2 < 8; it2++) {
        const int c = it2 * 256 + t;          // 0..2047
        const int kg = c >> 4, r16 = c & 15;
        const unsigned long long val = *reinterpret_cast<const unsigned long long*>(
            &tile[r16 * PREP_PITCH_B + kg * 8]);
        *reinterpret_cast<unsigned long long*>(&dst[(size_t)c * 8]) = val;
    }
    if (t < 16) {
        float sq = redbuf[t * 4] + redbuf[t * 4 + 1] +
                   redbuf[t * 4 + 2] + redbuf[t * 4 + 3];
        const int row = rb * 16 + t;
        if (is_z) zsq[row] = sq; else esq[row] = sq;
    }
}

// ---------------------------------------------------------------------------
// gemm_min (fp8, 128x128, CHAMPION — R14 verbatim): single-barrier
// double-buffered A-DMA pipeline, K-stage=128 (8 stages, 8 barriers,
// 64 MFMA/barrier/wave). A via LDS (ds_read_b64 at lane*8, 2-way alias =
// free), B direct from global (dwordx2 lane-linear).
// ~860 TF = the documented m97-family HIP plateau; bytes (R14), occupancy
// (R15), conflicts (R9), fences (R5), barriers (R6) all individually
// tested — this configuration is the measured optimum.
// 256 thr = 4 waves (2x2 of 64x64), grid (32,32), 4 blocks/CU.
// ---------------------------------------------------------------------------
__global__ __launch_bounds__(256, 4) void gemm_min_kernel(
    const uint8_t* __restrict__ zb, const uint8_t* __restrict__ eb,
    const float* __restrict__ zsq, unsigned* __restrict__ min_enc) {
    __shared__ __align__(16) uint8_t As[32768];  // 2 x 16 KB (8 segs x 2 KB)
    __shared__ float zsq_s[128];
    __shared__ float colmin[2][128];

    const int t = threadIdx.x;        // 0..255
    const int bx = blockIdx.x;        // code (col) block
    const int by = blockIdx.y;        // point (row) block
    const int lane = t & 63;
    const int w = t >> 6;             // 0..3
    const int wm = w >> 1, wn = w & 1;
    const int lrow = lane & 15;
    const int q = lane >> 4;

    if (t < 128) zsq_s[t] = zsq[by * 128 + t];

    f32x4 acc[4][4];
    #pragma unroll
    for (int i = 0; i < 4; i++)
        #pragma unroll
        for (int j = 0; j < 4; j++) acc[i][j] = (f32x4){0.f, 0.f, 0.f, 0.f};

    // A staging: per stage 16 KB (8 segs x 2 KB run). Instr j (0..3) = 4 KB:
    // waves {0,1} -> seg 2j, waves {2,3} -> seg 2j+1; inner = (t&127)*16.
    const int seg_half = t >> 7;            // 0..1
    const int inner = (t & 127) * 16;       // byte offset in 2 KB run
    const size_t a_seg0 = (size_t)(by * 8) * 16384;

    // B base: lane byte addr = lane*8 (lane-linear 512 B per fragment read).
    const uint8_t* b_base =
        eb + (size_t)(bx * 8 + wn * 4) * 16384 + lane * 8;

#define DMA_STAGE(st_)                                                        \
    {                                                                         \
        const int buf_ = ((st_) & 1) * 16384;                                 \
        const int koff_ = (st_) * 2048;  /* byte offset within seg */         \
        _Pragma("unroll")                                                     \
        for (int j = 0; j < 4; j++) {                                         \
            const uint8_t* ga = zb + a_seg0 +                                 \
                (size_t)(j * 2 + seg_half) * 16384 + koff_ + inner;           \
            __builtin_amdgcn_global_load_lds(                                 \
                (const __attribute__((address_space(1))) void*)ga,            \
                (__attribute__((address_space(3))) void*)(As + buf_ +         \
                    (j * 2 + seg_half) * 2048 + inner), 16, 0, 0);            \
        }                                                                     \
    }

    DMA_STAGE(0);
    for (int st = 0; st < 8; st++) {
        __syncthreads();                 // drains DMA(st)
        if (st < 7) DMA_STAGE(st + 1);   // overlaps with compute(st)
        const int buf = (st & 1) * 16384;
        const int koff = st * 2048;
        #pragma unroll
        for (int sl = 0; sl < 4; sl++) {   // four K=32 slices
            long a[4], bb[4];
            #pragma unroll
            for (int an = 0; an < 4; an++)
                bb[an] = *(const long*)(b_base + (size_t)an * 16384 +
                                        koff + sl * 512);
            #pragma unroll
            for (int am = 0; am < 4; am++)
                a[am] = *(const long*)(As + buf + (wm * 4 + am) * 2048 +
                                       sl * 512 + lane * 8);
            #pragma unroll
            for (int am = 0; am < 4; am++)
                #pragma unroll
                for (int an = 0; an < 4; an++)
                    acc[am][an] = __builtin_amdgcn_mfma_f32_16x16x32_fp8_fp8(
                        a[am], bb[an], acc[am][an], 0, 0, 0);
        }
    }
#undef DMA_STAGE

    __syncthreads();

    // Epilogue (proven; C/D layout shape-determined): row = q*4+r, col = lrow.
    #pragma unroll
    for (int an = 0; an < 4; an++) {
        float v = 3.4e38f;
        #pragma unroll
        for (int am = 0; am < 4; am++) {
            const int rbase = wm * 64 + am * 16 + q * 4;
            f32x4 c = acc[am][an];
            v = fminf(v, zsq_s[rbase + 0] - 2.f * c[0]);
            v = fminf(v, zsq_s[rbase + 1] - 2.f * c[1]);
            v = fminf(v, zsq_s[rbase + 2] - 2.f * c[2]);
            v = fminf(v, zsq_s[rbase + 3] - 2.f * c[3]);
        }
        v = fminf(v, __shfl_xor(v, 16, 64));
        v = fminf(v, __shfl_xor(v, 32, 64));
        if (q == 0) colmin[wm][wn * 64 + an * 16 + lrow] = v;
    }
    __syncthreads();
    if (t < 128) {
        const float m = fminf(colmin[0][t], colmin[1][t]);
        atomicMin(&min_enc[bx * 128 + t], enc_f32(m));
    }
}

// ---------------------------------------------------------------------------
// finalize: mean_j (dec(min_enc[j]) + esq[j]) -> single fp32 scalar.
// ---------------------------------------------------------------------------
__global__ __launch_bounds__(256) void finalize_kernel(
    const unsigned* __restrict__ min_enc, const float* __restrict__ esq,
    float* __restrict__ out) {
    const int t = threadIdx.x;
    float s = 0.f;
    #pragma unroll
    for (int i = 0; i < M_CODES / 256; i++) {
        const int j = i * 256 + t;
        s += dec_f32(min_enc[j]) + esq[j];
    }
    #pragma unroll
    for (int off = 1; off < 64; off <<= 1) s += __shfl_xor(s, off, 64);
    __shared__ float red[4];
    if ((t & 63) == 0) red[t >> 6] = s;
    __syncthreads();
    if (t == 0) out[0] = (red[0] + red[1] + red[2] + red[3]) * (1.f / M_CODES);
}

extern "C" void kernel_launch(void* const* d_in, const int* in_sizes, int n_in,
                              void* d_out, int out_size, void* d_ws, size_t ws_size,
                              hipStream_t stream) {
    (void)in_sizes; (void)n_in; (void)out_size; (void)ws_size;
    const float* z = (const float*)d_in[0];
    const float* e = (const float*)d_in[1];
    char* ws = (char*)d_ws;
    uint8_t* zb = (uint8_t*)ws;                                          // 4 MB
    uint8_t* eb = (uint8_t*)(ws + ((size_t)4 << 20));                    // 4 MB
    float* zsq = (float*)(ws + ((size_t)8 << 20));                       // 16 KB
    float* esq = (float*)(ws + ((size_t)8 << 20) + 16384);               // 16 KB
    unsigned* min_enc = (unsigned*)(ws + ((size_t)8 << 20) + 32768);     // 16 KB

    prep_kernel<<<dim3(512), dim3(256), 0, stream>>>(
        z, e, zb, eb, zsq, esq, min_enc);
    gemm_min_kernel<<<dim3(32, 32), dim3(256), 0, stream>>>(
        zb, eb, zsq, min_enc);
    finalize_kernel<<<dim3(1), dim3(256), 0, stream>>>(min_enc, esq, (float*)d_out);
}